// Round 4
// baseline (9987.293 us; speedup 1.0000x reference)
//
#include <hip/hip_runtime.h>
#include <cstdint>
#include <cstddef>

#define NBATCH  8
#define NPTS    8192
#define NFEAT   64
#define NPOINT  2048
#define NSAMPLE 32

// ---------------------------------------------------------------------------
// prep: fold BN into weights (y = dot*s + t), transpose to [c][o]
// ---------------------------------------------------------------------------
__global__ void prep_kernel(const float* __restrict__ w1, const float* __restrict__ b1,
                            const float* __restrict__ g1, const float* __restrict__ bb1,
                            const float* __restrict__ m1, const float* __restrict__ v1,
                            const float* __restrict__ w2, const float* __restrict__ b2,
                            const float* __restrict__ g2, const float* __restrict__ bb2,
                            const float* __restrict__ m2, const float* __restrict__ v2,
                            const float* __restrict__ w3, const float* __restrict__ b3,
                            const float* __restrict__ g3, const float* __restrict__ bb3,
                            const float* __restrict__ m3, const float* __restrict__ v3,
                            float* __restrict__ wbuf) {
    int i = blockIdx.x * 256 + threadIdx.x;
    if (i < 4288) {
        int o = i & 63, c = i >> 6;
        float s = g1[o] / sqrtf(v1[o] + 1e-5f);
        wbuf[i] = w1[o * 67 + c] * s;
    } else if (i < 4352) {
        int o = i - 4288;
        float s = g1[o] / sqrtf(v1[o] + 1e-5f);
        wbuf[i] = (b1[o] - m1[o]) * s + bb1[o];
    } else if (i < 8448) {
        int j = i - 4352; int o = j & 63, c = j >> 6;
        float s = g2[o] / sqrtf(v2[o] + 1e-5f);
        wbuf[i] = w2[o * 64 + c] * s;
    } else if (i < 8512) {
        int o = i - 8448;
        float s = g2[o] / sqrtf(v2[o] + 1e-5f);
        wbuf[i] = (b2[o] - m2[o]) * s + bb2[o];
    } else if (i < 16704) {
        int j = i - 8512; int o = j & 127, c = j >> 7;
        float s = g3[o] / sqrtf(v3[o] + 1e-5f);
        wbuf[i] = w3[o * 64 + c] * s;
    } else if (i < 16832) {
        int o = i - 16704;
        float s = g3[o] / sqrtf(v3[o] + 1e-5f);
        wbuf[i] = (b3[o] - m3[o]) * s + bb3[o];
    }
}

// ---------------------------------------------------------------------------
// FPS with exact spatial pruning.
// One block/batch, 512 threads. Points counting-sorted into an 8x8x8 LDS grid;
// thread t owns cell t (bbox center + inflated radius). Per iteration a cell
// skips iff a SAFE lower bound on dist^2(new centroid -> cell) exceeds the
// cell's max dd (then min(dd,d)=dd exactly for all members -> skip is exact,
// not approximate). dd updates use the same IEEE f32 recipe as numpy
// (__fsub/__fmul/__fadd, fminf); all argmax compares tie-break on ORIGINAL
// index, so sort order is semantically invisible. The unique winner thread
// publishes the next centroid via LDS (two barriers/iter, single-buffered).
// ---------------------------------------------------------------------------
__global__ __launch_bounds__(512, 2) void fps_kernel(const float* __restrict__ points,
                                                     int* __restrict__ fidx) {
    const int b = blockIdx.x;
    const int tid = threadIdx.x;
    const int lane = tid & 63;
    const int wv = tid >> 6;
    const float* __restrict__ pxg = points + (size_t)b * 3 * NPTS;
    const float* __restrict__ pyg = pxg + NPTS;
    const float* __restrict__ pzg = pyg + NPTS;

    __shared__ float sx[NPTS], sy[NPTS], sz[NPTS];   // 96 KB sorted coords
    __shared__ float sdd[NPTS];                      // 32 KB running min-dist^2
    __shared__ unsigned short sorig[NPTS];           // 16 KB original indices
    __shared__ int cnt[512];                         // counts, then cursors
    __shared__ int cellstart[513];
    __shared__ float wbv[8];
    __shared__ int   wbo[8];
    __shared__ float cs[3];

    // ---- load 16 points/thread, count cells ----
    float px[16], py[16], pz[16];
    cnt[tid] = 0;
#pragma unroll
    for (int j = 0; j < 16; ++j) {
        int n = tid + 512 * j;
        px[j] = pxg[n]; py[j] = pyg[n]; pz[j] = pzg[n];
    }
    __syncthreads();
#pragma unroll
    for (int j = 0; j < 16; ++j) {
        int cxi = min((int)(px[j] * 8.0f), 7);
        int cyi = min((int)(py[j] * 8.0f), 7);
        int czi = min((int)(pz[j] * 8.0f), 7);
        atomicAdd(&cnt[(cxi << 6) | (cyi << 3) | czi], 1);
    }
    __syncthreads();
    // ---- exclusive prefix over 512 counts (wave 0: 8 serial x 64-lane scan) ----
    if (tid < 64) {
        int base = tid * 8;
        int loc[8]; int s = 0;
#pragma unroll
        for (int k = 0; k < 8; ++k) { loc[k] = cnt[base + k]; s += loc[k]; }
        int inc = s;
#pragma unroll
        for (int off = 1; off < 64; off <<= 1) {
            int t = __shfl_up(inc, off);
            if (lane >= off) inc += t;
        }
        int run = inc - s;
#pragma unroll
        for (int k = 0; k < 8; ++k) { cellstart[base + k] = run; run += loc[k]; }
        if (tid == 63) cellstart[512] = run;
    }
    __syncthreads();
    cnt[tid] = cellstart[tid];    // reuse as write cursor
    __syncthreads();
    // ---- scatter (order within cell irrelevant: compares use orig idx) ----
#pragma unroll
    for (int j = 0; j < 16; ++j) {
        int n = tid + 512 * j;
        int cxi = min((int)(px[j] * 8.0f), 7);
        int cyi = min((int)(py[j] * 8.0f), 7);
        int czi = min((int)(pz[j] * 8.0f), 7);
        int pos = atomicAdd(&cnt[(cxi << 6) | (cyi << 3) | czi], 1);
        sx[pos] = px[j]; sy[pos] = py[j]; sz[pos] = pz[j];
        sorig[pos] = (unsigned short)n;
        sdd[pos] = 1e10f;
    }
    __syncthreads();
    // ---- per-cell bbox + cache init (argmax over all-equal dd = min orig) ----
    const int p0 = cellstart[tid], p1 = cellstart[tid + 1];
    float ccx = 0.f, ccy = 0.f, ccz = 0.f, rr = 0.f;
    float bestv = -1.0f; int besto = 0x7fffffff; int bestp = p0;
    if (p1 > p0) {
        float mnx = 1e30f, mny = 1e30f, mnz = 1e30f;
        float mxx = -1e30f, mxy = -1e30f, mxz = -1e30f;
        for (int p = p0; p < p1; ++p) {
            float x = sx[p], y = sy[p], z = sz[p];
            mnx = fminf(mnx, x); mxx = fmaxf(mxx, x);
            mny = fminf(mny, y); mxy = fmaxf(mxy, y);
            mnz = fminf(mnz, z); mxz = fmaxf(mxz, z);
            int o = (int)sorig[p];
            if (o < besto) { besto = o; bestp = p; }
        }
        ccx = (mnx + mxx) * 0.5f; ccy = (mny + mxy) * 0.5f; ccz = (mnz + mxz) * 0.5f;
        float hx = (mxx - mnx) * 0.5f, hy = (mxy - mny) * 0.5f, hz = (mxz - mnz) * 0.5f;
        rr = sqrtf(hx * hx + hy * hy + hz * hz) * 1.0001f + 1e-7f;
        bestv = 1e10f;
    }
    // initial centroid = original point 0
    float cx = pxg[0], cy = pyg[0], cz = pzg[0];
    if (tid == 0) fidx[b * NPOINT] = 0;

    for (int i = 1; i < NPOINT; ++i) {
        bool active = false;
        if (p1 > p0) {
            float ddx = cx - ccx, ddy = cy - ccy, ddz = cz - ccz;
            float D = ddx * ddx + ddy * ddy + ddz * ddz;
            float lb = sqrtf(D) - rr;
            // skip only with ~100x safety margin over f32 bound error
            active = !(lb > 1e-3f && lb * lb * 0.999f > bestv);
        }
        if (active) {
            float bv = -1.0f; int bo = 0x7fffffff; int bp = p0;
            for (int p = p0; p < p1; ++p) {
                float dx = __fsub_rn(sx[p], cx);
                float dy = __fsub_rn(sy[p], cy);
                float dz = __fsub_rn(sz[p], cz);
                float d  = __fadd_rn(__fadd_rn(__fmul_rn(dx, dx), __fmul_rn(dy, dy)),
                                     __fmul_rn(dz, dz));
                float nd = fminf(sdd[p], d);
                sdd[p] = nd;
                int o = (int)sorig[p];
                bool take = (nd > bv) || (nd == bv && o < bo);
                bv = take ? nd : bv; bo = take ? o : bo; bp = take ? p : bp;
            }
            bestv = bv; besto = bo; bestp = bp;
        }
        unsigned long long act = __ballot(active);
        if (act) {   // wave-uniform: re-reduce all 64 lane caches
            float v = bestv; int o = besto;
#pragma unroll
            for (int off = 32; off >= 1; off >>= 1) {
                float ov = __shfl_down(v, off);
                int   oo = __shfl_down(o, off);
                bool take = (ov > v) || (ov == v && oo < o);
                v = take ? ov : v; o = take ? oo : o;
            }
            if (lane == 0) { wbv[wv] = v; wbo[wv] = o; }
        }  // else: LDS slot already holds this wave's unchanged best
        __syncthreads();
        float M = wbv[0]; int I = wbo[0];
#pragma unroll
        for (int k = 1; k < 8; ++k) {
            float v = wbv[k]; int o = wbo[k];
            bool take = (v > M) || (v == M && o < I);
            M = take ? v : M; I = take ? o : I;
        }
        if (bestv == M && besto == I) {   // unique winner (orig idx unique)
            cs[0] = sx[bestp]; cs[1] = sy[bestp]; cs[2] = sz[bestp];
            fidx[b * NPOINT + i] = I;
        }
        __syncthreads();
        cx = cs[0]; cy = cs[1]; cz = cs[2];
    }
}

// ---------------------------------------------------------------------------
// Ball query: one wave per query. d = (qq+pp) - 2*qp, compare vs 0.04f.
// qp is the K=3 einsum/dot -> ascending FMA chain (verified exact in R1).
// ---------------------------------------------------------------------------
__global__ __launch_bounds__(256) void bq_kernel(const float* __restrict__ points,
                                                 const int* __restrict__ fidx,
                                                 int* __restrict__ ballidx,
                                                 float* __restrict__ out_xyz) {
    const int lane = threadIdx.x & 63;
    const int gw = (blockIdx.x << 2) + (threadIdx.x >> 6);
    const int b = gw >> 11;
    const int q = gw & 2047;
    const float* __restrict__ pxg = points + (size_t)b * 3 * NPTS;
    const float* __restrict__ pyg = pxg + NPTS;
    const float* __restrict__ pzg = pyg + NPTS;
    const int qi = fidx[b * NPOINT + q];
    const float qx = pxg[qi], qy = pyg[qi], qz = pzg[qi];
    const float qq = __fadd_rn(__fadd_rn(__fmul_rn(qx, qx), __fmul_rn(qy, qy)),
                               __fmul_rn(qz, qz));
    int* __restrict__ out = ballidx + ((size_t)(b * NPOINT + q)) * NSAMPLE;
    int have = 0;
    int first = -1;
    for (int base = 0; base < NPTS && have < NSAMPLE; base += 64) {
        const int n = base + lane;
        float x = pxg[n], y = pyg[n], z = pzg[n];
        float pp = __fadd_rn(__fadd_rn(__fmul_rn(x, x), __fmul_rn(y, y)), __fmul_rn(z, z));
        float qp = __builtin_fmaf(qz, z, __builtin_fmaf(qy, y, __fmul_rn(qx, x)));
        float d  = __fsub_rn(__fadd_rn(qq, pp), __fmul_rn(2.0f, qp));
        bool inb = d < 0.04f;   // f32(0.2*0.2) == 0.04f
        unsigned long long mask = __ballot(inb);
        if (mask) {
            if (first < 0) first = base + __ffsll(mask) - 1;
            if (inb) {
                int slot = have + (int)__popcll(mask & ((1ull << lane) - 1ull));
                if (slot < NSAMPLE) out[slot] = n;
            }
            have += (int)__popcll(mask);
        }
    }
    for (int s = have + lane; s < NSAMPLE; s += 64) out[s] = first;
    if (lane == 0) {
        float* o0 = out_xyz + (size_t)b * 3 * NPOINT + q;
        o0[0] = qx; o0[NPOINT] = qy; o0[2 * NPOINT] = qz;
    }
}

// ---------------------------------------------------------------------------
// Fused gather + 3-layer MLP (BN folded) + max-pool. One query per block,
// 256 threads. LDS tiles with stride 36 (float4-aligned, writes only 8-way).
// ---------------------------------------------------------------------------
#define XS 36
__global__ __launch_bounds__(256) void mlp_kernel(const float* __restrict__ feats,
                                                  const float* __restrict__ points,
                                                  const int* __restrict__ fidx,
                                                  const int* __restrict__ ballidx,
                                                  const float* __restrict__ wbuf,
                                                  float* __restrict__ out) {
    __shared__ float xT[67 * XS];   // [c][k], also reused for y2
    __shared__ float yA[64 * XS];   // y1, also reused for final partial max
    __shared__ float wl[8192];      // current layer's folded weights [c][o]
    __shared__ float bl[128];
    __shared__ int   il[32];
    __shared__ float qv[3];
    const int tid = threadIdx.x;
    const int bq = blockIdx.x;
    const int b = bq >> 11, q = bq & 2047;
    const float* __restrict__ pb = points + (size_t)b * 3 * NPTS;

    if (tid < 32) il[tid] = ballidx[((size_t)(b * NPOINT + q)) * NSAMPLE + tid];
    if (tid < 3)  qv[tid] = pb[(size_t)tid * NPTS + fidx[b * NPOINT + q]];
    for (int i = tid; i < 4288; i += 256) wl[i] = wbuf[i];
    if (tid < 64) bl[tid] = wbuf[4288 + tid];
    __syncthreads();

    // build xT: rows 0..2 = grouped_xyz, rows 3..66 = gathered features
    if (tid < 32) {
        int n = il[tid];
        xT[0 * XS + tid] = pb[n] - qv[0];
        xT[1 * XS + tid] = pb[NPTS + n] - qv[1];
        xT[2 * XS + tid] = pb[2 * NPTS + n] - qv[2];
    }
    {
        int k = tid & 31, fg = tid >> 5;
        int n = il[k];
        const float* fb = feats + ((size_t)b * NFEAT + fg * 8) * NPTS + n;
#pragma unroll
        for (int u = 0; u < 8; ++u) xT[(3 + fg * 8 + u) * XS + k] = fb[(size_t)u * NPTS];
    }
    __syncthreads();

    const int o = tid & 63, kb = tid >> 6;
    float acc[8];
    // ---- layer 1: 67 -> 64 ----
#pragma unroll
    for (int j = 0; j < 8; ++j) acc[j] = 0.f;
    for (int c = 0; c < 67; ++c) {
        float wv = wl[c * 64 + o];
        const float4* xp = (const float4*)&xT[c * XS + kb * 8];
        float4 a0 = xp[0], a1 = xp[1];
        acc[0] = fmaf(wv, a0.x, acc[0]); acc[1] = fmaf(wv, a0.y, acc[1]);
        acc[2] = fmaf(wv, a0.z, acc[2]); acc[3] = fmaf(wv, a0.w, acc[3]);
        acc[4] = fmaf(wv, a1.x, acc[4]); acc[5] = fmaf(wv, a1.y, acc[5]);
        acc[6] = fmaf(wv, a1.z, acc[6]); acc[7] = fmaf(wv, a1.w, acc[7]);
    }
    {
        float t = bl[o];
#pragma unroll
        for (int j = 0; j < 8; ++j) {
            float y = acc[j] + t;
            y = y > 0.f ? y : 0.2f * y;
            yA[o * XS + kb * 8 + j] = y;
        }
    }
    __syncthreads();
    for (int i = tid; i < 4096; i += 256) wl[i] = wbuf[4352 + i];
    if (tid < 64) bl[tid] = wbuf[8448 + tid];
    __syncthreads();

    // ---- layer 2: 64 -> 64 ----
#pragma unroll
    for (int j = 0; j < 8; ++j) acc[j] = 0.f;
    for (int c = 0; c < 64; ++c) {
        float wv = wl[c * 64 + o];
        const float4* xp = (const float4*)&yA[c * XS + kb * 8];
        float4 a0 = xp[0], a1 = xp[1];
        acc[0] = fmaf(wv, a0.x, acc[0]); acc[1] = fmaf(wv, a0.y, acc[1]);
        acc[2] = fmaf(wv, a0.z, acc[2]); acc[3] = fmaf(wv, a0.w, acc[3]);
        acc[4] = fmaf(wv, a1.x, acc[4]); acc[5] = fmaf(wv, a1.y, acc[5]);
        acc[6] = fmaf(wv, a1.z, acc[6]); acc[7] = fmaf(wv, a1.w, acc[7]);
    }
    {
        float t = bl[o];
#pragma unroll
        for (int j = 0; j < 8; ++j) {
            float y = acc[j] + t;
            y = y > 0.f ? y : 0.2f * y;
            xT[o * XS + kb * 8 + j] = y;   // y2 into xT (xT reads all done)
        }
    }
    __syncthreads();
    for (int i = tid; i < 8192; i += 256) wl[i] = wbuf[8512 + i];
    if (tid < 128) bl[tid] = wbuf[16704 + tid];
    __syncthreads();

    // ---- layer 3: 64 -> 128, fused max over k ----
    const int o3 = tid & 127, kb3 = tid >> 7;
    float a3[16];
#pragma unroll
    for (int j = 0; j < 16; ++j) a3[j] = 0.f;
    for (int c = 0; c < 64; ++c) {
        float wv = wl[c * 128 + o3];
        const float4* xp = (const float4*)&xT[c * XS + kb3 * 16];
        float4 x0 = xp[0], x1 = xp[1], x2 = xp[2], x3 = xp[3];
        a3[0]  = fmaf(wv, x0.x, a3[0]);  a3[1]  = fmaf(wv, x0.y, a3[1]);
        a3[2]  = fmaf(wv, x0.z, a3[2]);  a3[3]  = fmaf(wv, x0.w, a3[3]);
        a3[4]  = fmaf(wv, x1.x, a3[4]);  a3[5]  = fmaf(wv, x1.y, a3[5]);
        a3[6]  = fmaf(wv, x1.z, a3[6]);  a3[7]  = fmaf(wv, x1.w, a3[7]);
        a3[8]  = fmaf(wv, x2.x, a3[8]);  a3[9]  = fmaf(wv, x2.y, a3[9]);
        a3[10] = fmaf(wv, x2.z, a3[10]); a3[11] = fmaf(wv, x2.w, a3[11]);
        a3[12] = fmaf(wv, x3.x, a3[12]); a3[13] = fmaf(wv, x3.y, a3[13]);
        a3[14] = fmaf(wv, x3.z, a3[14]); a3[15] = fmaf(wv, x3.w, a3[15]);
    }
    {
        float t = bl[o3];
        float m = -3.4e38f;
#pragma unroll
        for (int j = 0; j < 16; ++j) {
            float y = a3[j] + t;
            y = y > 0.f ? y : 0.2f * y;
            m = fmaxf(m, y);
        }
        yA[o3 * 2 + kb3] = m;
    }
    __syncthreads();
    if (tid < 128) {
        float r = fmaxf(yA[tid * 2], yA[tid * 2 + 1]);
        out[((size_t)b * 128 + tid) * NPOINT + q] = r;
    }
}

// ---------------------------------------------------------------------------
extern "C" void kernel_launch(void* const* d_in, const int* in_sizes, int n_in,
                              void* d_out, int out_size, void* d_ws, size_t ws_size,
                              hipStream_t stream) {
    (void)in_sizes; (void)n_in; (void)out_size; (void)ws_size;
    const float* feats  = (const float*)d_in[0];
    const float* points = (const float*)d_in[1];
    const float* w1  = (const float*)d_in[2];
    const float* b1  = (const float*)d_in[3];
    const float* g1  = (const float*)d_in[4];
    const float* bb1 = (const float*)d_in[5];
    const float* m1  = (const float*)d_in[6];
    const float* v1  = (const float*)d_in[7];
    const float* w2  = (const float*)d_in[8];
    const float* b2  = (const float*)d_in[9];
    const float* g2  = (const float*)d_in[10];
    const float* bb2 = (const float*)d_in[11];
    const float* m2  = (const float*)d_in[12];
    const float* v2  = (const float*)d_in[13];
    const float* w3  = (const float*)d_in[14];
    const float* b3  = (const float*)d_in[15];
    const float* g3  = (const float*)d_in[16];
    const float* bb3 = (const float*)d_in[17];
    const float* m3  = (const float*)d_in[18];
    const float* v3  = (const float*)d_in[19];

    float* out = (float*)d_out;
    char*  ws  = (char*)d_ws;
    int*   fidx    = (int*)ws;                           // 8*2048 int = 64 KB
    int*   ballidx = (int*)(ws + 65536);                 // 8*2048*32 int = 2 MB
    float* wbuf    = (float*)(ws + 65536 + 2097152);     // 16832 floats
    float* out_xyz = out + (size_t)NBATCH * 128 * NPOINT;

    hipLaunchKernelGGL(prep_kernel, dim3(66), dim3(256), 0, stream,
                       w1, b1, g1, bb1, m1, v1, w2, b2, g2, bb2, m2, v2,
                       w3, b3, g3, bb3, m3, v3, wbuf);
    hipLaunchKernelGGL(fps_kernel, dim3(NBATCH), dim3(512), 0, stream, points, fidx);
    hipLaunchKernelGGL(bq_kernel, dim3(16384 / 4), dim3(256), 0, stream,
                       points, fidx, ballidx, out_xyz);
    hipLaunchKernelGGL(mlp_kernel, dim3(NBATCH * NPOINT), dim3(256), 0, stream,
                       feats, points, fidx, ballidx, wbuf, out);
}

// Round 5
// 3831.258 us; speedup vs baseline: 2.6068x; 2.6068x over previous
//
#include <hip/hip_runtime.h>
#include <cstdint>
#include <cstddef>

#define NBATCH  8
#define NPTS    8192
#define NFEAT   64
#define NPOINT  2048
#define NSAMPLE 32

// ---------------------------------------------------------------------------
// prep: fold BN into weights (y = dot*s + t), transpose to [c][o]
// ---------------------------------------------------------------------------
__global__ void prep_kernel(const float* __restrict__ w1, const float* __restrict__ b1,
                            const float* __restrict__ g1, const float* __restrict__ bb1,
                            const float* __restrict__ m1, const float* __restrict__ v1,
                            const float* __restrict__ w2, const float* __restrict__ b2,
                            const float* __restrict__ g2, const float* __restrict__ bb2,
                            const float* __restrict__ m2, const float* __restrict__ v2,
                            const float* __restrict__ w3, const float* __restrict__ b3,
                            const float* __restrict__ g3, const float* __restrict__ bb3,
                            const float* __restrict__ m3, const float* __restrict__ v3,
                            float* __restrict__ wbuf) {
    int i = blockIdx.x * 256 + threadIdx.x;
    if (i < 4288) {
        int o = i & 63, c = i >> 6;
        float s = g1[o] / sqrtf(v1[o] + 1e-5f);
        wbuf[i] = w1[o * 67 + c] * s;
    } else if (i < 4352) {
        int o = i - 4288;
        float s = g1[o] / sqrtf(v1[o] + 1e-5f);
        wbuf[i] = (b1[o] - m1[o]) * s + bb1[o];
    } else if (i < 8448) {
        int j = i - 4352; int o = j & 63, c = j >> 6;
        float s = g2[o] / sqrtf(v2[o] + 1e-5f);
        wbuf[i] = w2[o * 64 + c] * s;
    } else if (i < 8512) {
        int o = i - 8448;
        float s = g2[o] / sqrtf(v2[o] + 1e-5f);
        wbuf[i] = (b2[o] - m2[o]) * s + bb2[o];
    } else if (i < 16704) {
        int j = i - 8512; int o = j & 127, c = j >> 7;
        float s = g3[o] / sqrtf(v3[o] + 1e-5f);
        wbuf[i] = w3[o * 64 + c] * s;
    } else if (i < 16832) {
        int o = i - 16704;
        float s = g3[o] / sqrtf(v3[o] + 1e-5f);
        wbuf[i] = (b3[o] - m3[o]) * s + bb3[o];
    }
}

// ---------------------------------------------------------------------------
// FPS with exact spatial pruning, worklist-scheduled.
// Counting-sort points into 512 cells (8x8x8) in LDS. Per iteration:
//  1) thread t = cell t: exact skip test (safe lower bound vs cached max dd);
//     active cells reset their u64 key and append to a compact worklist.
//  2) worklist processed cooperatively: 16 consecutive lanes per cell ->
//     consecutive LDS addresses (no 32-way conflicts, no idle-wave scans).
//     Per point: exact-IEEE dd update; per-cell argmax cache rebuilt via LDS
//     atomicMax on key = (nd_bits<<26)|((8191-orig)<<13)|pos  (f32>=0 bits
//     are order-monotone; max key == max nd, tie -> min orig == numpy argmax).
//  3) global winner = u64 shfl reduce over 512 cell keys + 8-partial scan.
// Skip is EXACT: skipping requires lower-bound > cell max dd, so min(dd,d)=dd
// for every member; margins (1e-3 floor, 0.999 scale, inflated radius) exceed
// worst-case f32 bound error by ~100x. Validated in R4 (absmax unchanged).
// ---------------------------------------------------------------------------
__global__ __launch_bounds__(512, 2) void fps_kernel(const float* __restrict__ points,
                                                     int* __restrict__ fidx) {
    const int b = blockIdx.x;
    const int tid = threadIdx.x;
    const int lane = tid & 63;
    const int wv = tid >> 6;
    const float* __restrict__ pxg = points + (size_t)b * 3 * NPTS;
    const float* __restrict__ pyg = pxg + NPTS;
    const float* __restrict__ pzg = pyg + NPTS;

    __shared__ float sx[NPTS], sy[NPTS], sz[NPTS];   // 96 KB sorted coords
    __shared__ float sdd[NPTS];                      // 32 KB running min-dist^2
    __shared__ unsigned short sorig[NPTS];           // 16 KB original indices
    __shared__ int cellstart[513];
    __shared__ int cnt[512];
    __shared__ unsigned long long cellkey[512];      // cached per-cell argmax
    __shared__ unsigned short wl[2][512];            // worklist (parity dbuf)
    __shared__ int wcnt[2];
    __shared__ unsigned long long pk[2][8];          // per-wave reduce partials

    // ---- setup: load, count, prefix, scatter ----
    float px[16], py[16], pz[16];
    int pos16[16];
    cnt[tid] = 0;
    cellkey[tid] = 0ull;
    if (tid < 2) wcnt[tid] = 0;
#pragma unroll
    for (int j = 0; j < 16; ++j) {
        int n = tid + 512 * j;
        px[j] = pxg[n]; py[j] = pyg[n]; pz[j] = pzg[n];
    }
    __syncthreads();
#pragma unroll
    for (int j = 0; j < 16; ++j) {
        int cxi = min((int)(px[j] * 8.0f), 7);
        int cyi = min((int)(py[j] * 8.0f), 7);
        int czi = min((int)(pz[j] * 8.0f), 7);
        atomicAdd(&cnt[(cxi << 6) | (cyi << 3) | czi], 1);
    }
    __syncthreads();
    if (tid < 64) {   // exclusive prefix over 512 counts (wave 0)
        int base = tid * 8;
        int loc[8]; int s = 0;
#pragma unroll
        for (int k = 0; k < 8; ++k) { loc[k] = cnt[base + k]; s += loc[k]; }
        int inc = s;
#pragma unroll
        for (int off = 1; off < 64; off <<= 1) {
            int t = __shfl_up(inc, off);
            if (lane >= off) inc += t;
        }
        int run = inc - s;
#pragma unroll
        for (int k = 0; k < 8; ++k) { cellstart[base + k] = run; run += loc[k]; }
        if (tid == 63) cellstart[512] = run;
    }
    __syncthreads();
    cnt[tid] = cellstart[tid];    // reuse as write cursor
    __syncthreads();
#pragma unroll
    for (int j = 0; j < 16; ++j) {
        int n = tid + 512 * j;
        int cxi = min((int)(px[j] * 8.0f), 7);
        int cyi = min((int)(py[j] * 8.0f), 7);
        int czi = min((int)(pz[j] * 8.0f), 7);
        int pos = atomicAdd(&cnt[(cxi << 6) | (cyi << 3) | czi], 1);
        sx[pos] = px[j]; sy[pos] = py[j]; sz[pos] = pz[j];
        sorig[pos] = (unsigned short)n;
        sdd[pos] = 1e10f;
        pos16[j] = pos;
    }
    __syncthreads();
    // init per-cell keys: nd uniform 1e10 -> max key == min orig (numpy argmax)
#pragma unroll
    for (int j = 0; j < 16; ++j) {
        int n = tid + 512 * j;
        int cxi = min((int)(px[j] * 8.0f), 7);
        int cyi = min((int)(py[j] * 8.0f), 7);
        int czi = min((int)(pz[j] * 8.0f), 7);
        int c = (cxi << 6) | (cyi << 3) | czi;
        unsigned long long key =
            ((unsigned long long)(unsigned)__float_as_int(1e10f) << 26)
          | ((unsigned long long)(8191 - n) << 13) | (unsigned long long)pos16[j];
        atomicMax(&cellkey[c], key);
    }
    float cx = pxg[0], cy = pyg[0], cz = pzg[0];   // broadcast loads
    if (tid == 0) fidx[b * NPOINT] = 0;
    __syncthreads();

    const int p0 = cellstart[tid], p1c = cellstart[tid + 1];
    const float ccx = (float)((tid >> 6) & 7) * 0.125f + 0.0625f;
    const float ccy = (float)((tid >> 3) & 7) * 0.125f + 0.0625f;
    const float ccz = (float)(tid & 7) * 0.125f + 0.0625f;
    const int kk = tid & 15;

    for (int i = 1; i < NPOINT; ++i) {
        const int par = i & 1;
        // ---- 1) bound test + worklist append ----
        unsigned long long ck = cellkey[tid];
        float bestv = __uint_as_float((unsigned)(ck >> 26));
        float ddx = cx - ccx, ddy = cy - ccy, ddz = cz - ccz;
        float D = ddx * ddx + ddy * ddy + ddz * ddz;
        float lb = sqrtf(D) - 0.108265f;   // inflated half-diagonal of 1/8 cube
        bool active = (p1c > p0) && !(lb > 1e-3f && lb * lb * 0.999f > bestv);
        if (active) cellkey[tid] = 0ull;   // rebuilt fresh below (values shrink)
        unsigned long long mask = __ballot(active);
        int wbase = 0;
        if (lane == 0 && mask) wbase = atomicAdd(&wcnt[par], (int)__popcll(mask));
        wbase = __shfl(wbase, 0);
        if (active) {
            int rank = (int)__popcll(mask & ((1ull << lane) - 1ull));
            wl[par][wbase + rank] = (unsigned short)tid;
        }
        __syncthreads();                   // A: worklist ready
        // ---- 2) cooperative processing: 16 lanes per active cell ----
        int nw = wcnt[par];
        for (int e = tid >> 4; e < nw; e += 32) {
            int c = wl[par][e];
            int q0 = cellstart[c], q1 = cellstart[c + 1];
            for (int p = q0 + kk; p < q1; p += 16) {
                float dx = __fsub_rn(sx[p], cx);
                float dy = __fsub_rn(sy[p], cy);
                float dz = __fsub_rn(sz[p], cz);
                float d  = __fadd_rn(__fadd_rn(__fmul_rn(dx, dx), __fmul_rn(dy, dy)),
                                     __fmul_rn(dz, dz));
                float nd = fminf(sdd[p], d);
                sdd[p] = nd;
                int o = (int)sorig[p];
                unsigned long long key =
                    ((unsigned long long)(unsigned)__float_as_int(nd) << 26)
                  | ((unsigned long long)(8191 - o) << 13) | (unsigned long long)p;
                atomicMax(&cellkey[c], key);
            }
        }
        if (tid == 0) wcnt[par ^ 1] = 0;   // reset other parity for iter i+1
        __syncthreads();                   // B: cellkey fresh
        // ---- 3) global argmax over 512 cell keys ----
        unsigned long long v = cellkey[tid];
#pragma unroll
        for (int off = 32; off >= 1; off >>= 1) {
            unsigned long long o = __shfl_down(v, off);
            v = (o > v) ? o : v;
        }
        if (lane == 0) pk[par][wv] = v;
        __syncthreads();                   // C: partials ready
        unsigned long long M = pk[par][0];
#pragma unroll
        for (int k = 1; k < 8; ++k) {
            unsigned long long t2 = pk[par][k];
            M = (t2 > M) ? t2 : M;
        }
        int P = (int)(M & 0x1FFFull);
        cx = sx[P]; cy = sy[P]; cz = sz[P];   // broadcast LDS reads
        if (tid == 0) fidx[b * NPOINT + i] = 8191 - (int)((M >> 13) & 0x1FFF);
    }
}

// ---------------------------------------------------------------------------
// Ball query: one wave per query. d = (qq+pp) - 2*qp, compare vs 0.04f.
// qp is the K=3 einsum/dot -> ascending FMA chain (verified exact in R1).
// ---------------------------------------------------------------------------
__global__ __launch_bounds__(256) void bq_kernel(const float* __restrict__ points,
                                                 const int* __restrict__ fidx,
                                                 int* __restrict__ ballidx,
                                                 float* __restrict__ out_xyz) {
    const int lane = threadIdx.x & 63;
    const int gw = (blockIdx.x << 2) + (threadIdx.x >> 6);
    const int b = gw >> 11;
    const int q = gw & 2047;
    const float* __restrict__ pxg = points + (size_t)b * 3 * NPTS;
    const float* __restrict__ pyg = pxg + NPTS;
    const float* __restrict__ pzg = pyg + NPTS;
    const int qi = fidx[b * NPOINT + q];
    const float qx = pxg[qi], qy = pyg[qi], qz = pzg[qi];
    const float qq = __fadd_rn(__fadd_rn(__fmul_rn(qx, qx), __fmul_rn(qy, qy)),
                               __fmul_rn(qz, qz));
    int* __restrict__ out = ballidx + ((size_t)(b * NPOINT + q)) * NSAMPLE;
    int have = 0;
    int first = -1;
    for (int base = 0; base < NPTS && have < NSAMPLE; base += 64) {
        const int n = base + lane;
        float x = pxg[n], y = pyg[n], z = pzg[n];
        float pp = __fadd_rn(__fadd_rn(__fmul_rn(x, x), __fmul_rn(y, y)), __fmul_rn(z, z));
        float qp = __builtin_fmaf(qz, z, __builtin_fmaf(qy, y, __fmul_rn(qx, x)));
        float d  = __fsub_rn(__fadd_rn(qq, pp), __fmul_rn(2.0f, qp));
        bool inb = d < 0.04f;   // f32(0.2*0.2) == 0.04f
        unsigned long long mask = __ballot(inb);
        if (mask) {
            if (first < 0) first = base + __ffsll(mask) - 1;
            if (inb) {
                int slot = have + (int)__popcll(mask & ((1ull << lane) - 1ull));
                if (slot < NSAMPLE) out[slot] = n;
            }
            have += (int)__popcll(mask);
        }
    }
    for (int s = have + lane; s < NSAMPLE; s += 64) out[s] = first;
    if (lane == 0) {
        float* o0 = out_xyz + (size_t)b * 3 * NPOINT + q;
        o0[0] = qx; o0[NPOINT] = qy; o0[2 * NPOINT] = qz;
    }
}

// ---------------------------------------------------------------------------
// Fused gather + 3-layer MLP (BN folded) + max-pool. One query per block,
// 256 threads. LDS tiles with stride 36 (float4-aligned, writes only 8-way).
// ---------------------------------------------------------------------------
#define XS 36
__global__ __launch_bounds__(256) void mlp_kernel(const float* __restrict__ feats,
                                                  const float* __restrict__ points,
                                                  const int* __restrict__ fidx,
                                                  const int* __restrict__ ballidx,
                                                  const float* __restrict__ wbuf,
                                                  float* __restrict__ out) {
    __shared__ float xT[67 * XS];   // [c][k], also reused for y2
    __shared__ float yA[64 * XS];   // y1, also reused for final partial max
    __shared__ float wl[8192];      // current layer's folded weights [c][o]
    __shared__ float bl[128];
    __shared__ int   il[32];
    __shared__ float qv[3];
    const int tid = threadIdx.x;
    const int bq = blockIdx.x;
    const int b = bq >> 11, q = bq & 2047;
    const float* __restrict__ pb = points + (size_t)b * 3 * NPTS;

    if (tid < 32) il[tid] = ballidx[((size_t)(b * NPOINT + q)) * NSAMPLE + tid];
    if (tid < 3)  qv[tid] = pb[(size_t)tid * NPTS + fidx[b * NPOINT + q]];
    for (int i = tid; i < 4288; i += 256) wl[i] = wbuf[i];
    if (tid < 64) bl[tid] = wbuf[4288 + tid];
    __syncthreads();

    // build xT: rows 0..2 = grouped_xyz, rows 3..66 = gathered features
    if (tid < 32) {
        int n = il[tid];
        xT[0 * XS + tid] = pb[n] - qv[0];
        xT[1 * XS + tid] = pb[NPTS + n] - qv[1];
        xT[2 * XS + tid] = pb[2 * NPTS + n] - qv[2];
    }
    {
        int k = tid & 31, fg = tid >> 5;
        int n = il[k];
        const float* fb = feats + ((size_t)b * NFEAT + fg * 8) * NPTS + n;
#pragma unroll
        for (int u = 0; u < 8; ++u) xT[(3 + fg * 8 + u) * XS + k] = fb[(size_t)u * NPTS];
    }
    __syncthreads();

    const int o = tid & 63, kb = tid >> 6;
    float acc[8];
    // ---- layer 1: 67 -> 64 ----
#pragma unroll
    for (int j = 0; j < 8; ++j) acc[j] = 0.f;
    for (int c = 0; c < 67; ++c) {
        float wv = wl[c * 64 + o];
        const float4* xp = (const float4*)&xT[c * XS + kb * 8];
        float4 a0 = xp[0], a1 = xp[1];
        acc[0] = fmaf(wv, a0.x, acc[0]); acc[1] = fmaf(wv, a0.y, acc[1]);
        acc[2] = fmaf(wv, a0.z, acc[2]); acc[3] = fmaf(wv, a0.w, acc[3]);
        acc[4] = fmaf(wv, a1.x, acc[4]); acc[5] = fmaf(wv, a1.y, acc[5]);
        acc[6] = fmaf(wv, a1.z, acc[6]); acc[7] = fmaf(wv, a1.w, acc[7]);
    }
    {
        float t = bl[o];
#pragma unroll
        for (int j = 0; j < 8; ++j) {
            float y = acc[j] + t;
            y = y > 0.f ? y : 0.2f * y;
            yA[o * XS + kb * 8 + j] = y;
        }
    }
    __syncthreads();
    for (int i = tid; i < 4096; i += 256) wl[i] = wbuf[4352 + i];
    if (tid < 64) bl[tid] = wbuf[8448 + tid];
    __syncthreads();

    // ---- layer 2: 64 -> 64 ----
#pragma unroll
    for (int j = 0; j < 8; ++j) acc[j] = 0.f;
    for (int c = 0; c < 64; ++c) {
        float wv = wl[c * 64 + o];
        const float4* xp = (const float4*)&yA[c * XS + kb * 8];
        float4 a0 = xp[0], a1 = xp[1];
        acc[0] = fmaf(wv, a0.x, acc[0]); acc[1] = fmaf(wv, a0.y, acc[1]);
        acc[2] = fmaf(wv, a0.z, acc[2]); acc[3] = fmaf(wv, a0.w, acc[3]);
        acc[4] = fmaf(wv, a1.x, acc[4]); acc[5] = fmaf(wv, a1.y, acc[5]);
        acc[6] = fmaf(wv, a1.z, acc[6]); acc[7] = fmaf(wv, a1.w, acc[7]);
    }
    {
        float t = bl[o];
#pragma unroll
        for (int j = 0; j < 8; ++j) {
            float y = acc[j] + t;
            y = y > 0.f ? y : 0.2f * y;
            xT[o * XS + kb * 8 + j] = y;   // y2 into xT (xT reads all done)
        }
    }
    __syncthreads();
    for (int i = tid; i < 8192; i += 256) wl[i] = wbuf[8512 + i];
    if (tid < 128) bl[tid] = wbuf[16704 + tid];
    __syncthreads();

    // ---- layer 3: 64 -> 128, fused max over k ----
    const int o3 = tid & 127, kb3 = tid >> 7;
    float a3[16];
#pragma unroll
    for (int j = 0; j < 16; ++j) a3[j] = 0.f;
    for (int c = 0; c < 64; ++c) {
        float wv = wl[c * 128 + o3];
        const float4* xp = (const float4*)&xT[c * XS + kb3 * 16];
        float4 x0 = xp[0], x1 = xp[1], x2 = xp[2], x3 = xp[3];
        a3[0]  = fmaf(wv, x0.x, a3[0]);  a3[1]  = fmaf(wv, x0.y, a3[1]);
        a3[2]  = fmaf(wv, x0.z, a3[2]);  a3[3]  = fmaf(wv, x0.w, a3[3]);
        a3[4]  = fmaf(wv, x1.x, a3[4]);  a3[5]  = fmaf(wv, x1.y, a3[5]);
        a3[6]  = fmaf(wv, x1.z, a3[6]);  a3[7]  = fmaf(wv, x1.w, a3[7]);
        a3[8]  = fmaf(wv, x2.x, a3[8]);  a3[9]  = fmaf(wv, x2.y, a3[9]);
        a3[10] = fmaf(wv, x2.z, a3[10]); a3[11] = fmaf(wv, x2.w, a3[11]);
        a3[12] = fmaf(wv, x3.x, a3[12]); a3[13] = fmaf(wv, x3.y, a3[13]);
        a3[14] = fmaf(wv, x3.z, a3[14]); a3[15] = fmaf(wv, x3.w, a3[15]);
    }
    {
        float t = bl[o3];
        float m = -3.4e38f;
#pragma unroll
        for (int j = 0; j < 16; ++j) {
            float y = a3[j] + t;
            y = y > 0.f ? y : 0.2f * y;
            m = fmaxf(m, y);
        }
        yA[o3 * 2 + kb3] = m;
    }
    __syncthreads();
    if (tid < 128) {
        float r = fmaxf(yA[tid * 2], yA[tid * 2 + 1]);
        out[((size_t)b * 128 + tid) * NPOINT + q] = r;
    }
}

// ---------------------------------------------------------------------------
extern "C" void kernel_launch(void* const* d_in, const int* in_sizes, int n_in,
                              void* d_out, int out_size, void* d_ws, size_t ws_size,
                              hipStream_t stream) {
    (void)in_sizes; (void)n_in; (void)out_size; (void)ws_size;
    const float* feats  = (const float*)d_in[0];
    const float* points = (const float*)d_in[1];
    const float* w1  = (const float*)d_in[2];
    const float* b1  = (const float*)d_in[3];
    const float* g1  = (const float*)d_in[4];
    const float* bb1 = (const float*)d_in[5];
    const float* m1  = (const float*)d_in[6];
    const float* v1  = (const float*)d_in[7];
    const float* w2  = (const float*)d_in[8];
    const float* b2  = (const float*)d_in[9];
    const float* g2  = (const float*)d_in[10];
    const float* bb2 = (const float*)d_in[11];
    const float* m2  = (const float*)d_in[12];
    const float* v2  = (const float*)d_in[13];
    const float* w3  = (const float*)d_in[14];
    const float* b3  = (const float*)d_in[15];
    const float* g3  = (const float*)d_in[16];
    const float* bb3 = (const float*)d_in[17];
    const float* m3  = (const float*)d_in[18];
    const float* v3  = (const float*)d_in[19];

    float* out = (float*)d_out;
    char*  ws  = (char*)d_ws;
    int*   fidx    = (int*)ws;                           // 8*2048 int = 64 KB
    int*   ballidx = (int*)(ws + 65536);                 // 8*2048*32 int = 2 MB
    float* wbuf    = (float*)(ws + 65536 + 2097152);     // 16832 floats
    float* out_xyz = out + (size_t)NBATCH * 128 * NPOINT;

    hipLaunchKernelGGL(prep_kernel, dim3(66), dim3(256), 0, stream,
                       w1, b1, g1, bb1, m1, v1, w2, b2, g2, bb2, m2, v2,
                       w3, b3, g3, bb3, m3, v3, wbuf);
    hipLaunchKernelGGL(fps_kernel, dim3(NBATCH), dim3(512), 0, stream, points, fidx);
    hipLaunchKernelGGL(bq_kernel, dim3(16384 / 4), dim3(256), 0, stream,
                       points, fidx, ballidx, out_xyz);
    hipLaunchKernelGGL(mlp_kernel, dim3(NBATCH * NPOINT), dim3(256), 0, stream,
                       feats, points, fidx, ballidx, wbuf, out);
}